// Round 6
// baseline (121.959 us; speedup 1.0000x reference)
//
#include <hip/hip_runtime.h>
#include <hip/hip_bf16.h>
#include <hip/hip_fp8.h>

// Problem shape (fixed by setup_inputs)
#define SEQ   16384
#define DIN_  2048
#define DOUT_ 1024
#define NE_   8
#define TPE   (SEQ / NE_)   // 2048 tokens per expert
#define NT    (DIN_ / 64)   // 32 K-tiles of 64

typedef __bf16 bf16x8 __attribute__((ext_vector_type(8)));
typedef __bf16 bf16x4 __attribute__((ext_vector_type(4)));
typedef float  f32x4  __attribute__((ext_vector_type(4)));

// async global->LDS, 16B per lane. LDS dest must be wave-linear (base + lane*16).
#define GLD(gp, lp) __builtin_amdgcn_global_load_lds( \
    (const __attribute__((address_space(1))) unsigned int*)(gp), \
    (__attribute__((address_space(3))) unsigned int*)(lp), 16, 0, 0)

// Reference fp8_round with the tile-wide divide hoisted: r = v*(1/scale)
__device__ __forceinline__ float fp8_round_dq_m(float v, float sinv, float s) {
    float r = v * sinv;
    r = fminf(fmaxf(r, -448.0f), 448.0f);
    __hip_fp8_e4m3 q(r);   // OCP e4m3fn, RNE, saturated
    return (float)q * s;
}

// ---------------- activation quant-dequant: 1x128 tiles, 2 rows per block ----------------
__global__ __launch_bounds__(256) void quant_x_kernel(const float* __restrict__ X,
                                                      __bf16* __restrict__ Xq) {
    const int t    = threadIdx.x;
    const int lane = t & 63;
    const int wave = t >> 6;
    const int tile = wave * 4 + (lane >> 4);   // 0..15
    const int sub  = lane & 15;
    const size_t off = (size_t)tile * 128 + sub * 8;

    const int row0 = blockIdx.x * 2;
    const float* pa = X + (size_t)row0 * DIN_ + off;
    const float* pb = X + (size_t)(row0 + 1) * DIN_ + off;

    float4 a0 = *(const float4*)pa;
    float4 a1 = *(const float4*)(pa + 4);
    float4 b0 = *(const float4*)pb;
    float4 b1 = *(const float4*)(pb + 4);

    float ma = fmaxf(fmaxf(fmaxf(fabsf(a0.x), fabsf(a0.y)), fmaxf(fabsf(a0.z), fabsf(a0.w))),
                     fmaxf(fmaxf(fabsf(a1.x), fabsf(a1.y)), fmaxf(fabsf(a1.z), fabsf(a1.w))));
    float mb = fmaxf(fmaxf(fmaxf(fabsf(b0.x), fabsf(b0.y)), fmaxf(fabsf(b0.z), fabsf(b0.w))),
                     fmaxf(fmaxf(fabsf(b1.x), fabsf(b1.y)), fmaxf(fabsf(b1.z), fabsf(b1.w))));
    #pragma unroll
    for (int off2 = 1; off2 < 16; off2 <<= 1) {
        ma = fmaxf(ma, __shfl_xor(ma, off2, 64));
        mb = fmaxf(mb, __shfl_xor(mb, off2, 64));
    }

    const float sa = fmaxf(ma, 1e-12f) / 448.0f, sia = 1.0f / sa;
    const float sb = fmaxf(mb, 1e-12f) / 448.0f, sib = 1.0f / sb;

    bf16x8 oa, ob;
    oa[0] = (__bf16)fp8_round_dq_m(a0.x, sia, sa);
    oa[1] = (__bf16)fp8_round_dq_m(a0.y, sia, sa);
    oa[2] = (__bf16)fp8_round_dq_m(a0.z, sia, sa);
    oa[3] = (__bf16)fp8_round_dq_m(a0.w, sia, sa);
    oa[4] = (__bf16)fp8_round_dq_m(a1.x, sia, sa);
    oa[5] = (__bf16)fp8_round_dq_m(a1.y, sia, sa);
    oa[6] = (__bf16)fp8_round_dq_m(a1.z, sia, sa);
    oa[7] = (__bf16)fp8_round_dq_m(a1.w, sia, sa);
    ob[0] = (__bf16)fp8_round_dq_m(b0.x, sib, sb);
    ob[1] = (__bf16)fp8_round_dq_m(b0.y, sib, sb);
    ob[2] = (__bf16)fp8_round_dq_m(b0.z, sib, sb);
    ob[3] = (__bf16)fp8_round_dq_m(b0.w, sib, sb);
    ob[4] = (__bf16)fp8_round_dq_m(b1.x, sib, sb);
    ob[5] = (__bf16)fp8_round_dq_m(b1.y, sib, sb);
    ob[6] = (__bf16)fp8_round_dq_m(b1.z, sib, sb);
    ob[7] = (__bf16)fp8_round_dq_m(b1.w, sib, sb);
    *(bf16x8*)(Xq + (size_t)row0 * DIN_ + off) = oa;
    *(bf16x8*)(Xq + (size_t)(row0 + 1) * DIN_ + off) = ob;
}

// ---------------- weight quant-dequant: 128x128 blocks ----------------
__global__ __launch_bounds__(256) void quant_w_kernel(const float* __restrict__ W,
                                                      __bf16* __restrict__ Wq) {
    const int rb = blockIdx.x >> 4;
    const int cb = blockIdx.x & 15;
    const int t  = threadIdx.x;

    const float* base = W + (size_t)(rb * 128) * DIN_ + cb * 128;
    const int r0 = t >> 5;
    const int c0 = (t & 31) * 4;

    float4 v[16];
    float m = 0.0f;
    #pragma unroll
    for (int i = 0; i < 16; ++i) {
        v[i] = *(const float4*)(base + (size_t)(i * 8 + r0) * DIN_ + c0);
        m = fmaxf(m, fmaxf(fmaxf(fabsf(v[i].x), fabsf(v[i].y)),
                           fmaxf(fabsf(v[i].z), fabsf(v[i].w))));
    }
    #pragma unroll
    for (int off = 1; off < 64; off <<= 1)
        m = fmaxf(m, __shfl_xor(m, off, 64));
    __shared__ float smx[4];
    if ((t & 63) == 0) smx[t >> 6] = m;
    __syncthreads();
    const float amax = fmaxf(fmaxf(smx[0], smx[1]), fmaxf(smx[2], smx[3]));
    const float s    = fmaxf(amax, 1e-12f) / 448.0f;
    const float sinv = 1.0f / s;

    __bf16* obase = Wq + (size_t)(rb * 128) * DIN_ + cb * 128;
    #pragma unroll
    for (int i = 0; i < 16; ++i) {
        bf16x4 o;
        o[0] = (__bf16)fp8_round_dq_m(v[i].x, sinv, s);
        o[1] = (__bf16)fp8_round_dq_m(v[i].y, sinv, s);
        o[2] = (__bf16)fp8_round_dq_m(v[i].z, sinv, s);
        o[3] = (__bf16)fp8_round_dq_m(v[i].w, sinv, s);
        *(bf16x4*)(obase + (size_t)(i * 8 + r0) * DIN_ + c0) = o;
    }
}

// ---------------- grouped GEMM: 256x256, BK=64, pre-read pipelined (counted lgkm) ----
// LDS 128 KiB = 8 kh-half regions [256 rows][64 B]:
//   A(buf,kh) @ (buf*2+kh)*16384 ; B(buf,kh) @ 65536 + (buf*2+kh)*16384.
// Pre-read schedule (reads issued ONE phase ahead, drain under MFMA):
//   ph4(kt-1): aA=A-kh0 m0-3 + b0=B-kh0   [8]   -> used ph1
//   ph1:       aB=A-kh0 m4-7              [4]   -> used ph2
//   ph2:       aA=A-kh1 m0-3 + b1=B-kh1   [8]   -> used ph3
//   ph3:       aB=A-kh1 m4-7              [4]   -> used ph4
// Counted waits: ph1 lgkm(4), ph2 lgkm(8), ph3 lgkm(4), ph4 lgkm(8|0).
// Stage slots (all barrier-separated from the region's drained last reader):
//   ph1: A-kh1(kt+1) | ph2: B-kh0(kt+2) | ph4: B-kh1(kt+2), A-kh0(kt+2)
// vmcnt gates placed just BEFORE the inter-phase barrier (barrier = release):
//   end-ph1: vmcnt(8) [tail kt==NT-1: 0]  -> A-kh1(kt), B-kh1(kt) landed for ph2 reads
//   end-ph3: vmcnt(4) [kt==NT-2: 2; kt==NT-1: none] -> A/B-kh0(kt+1) landed for ph4 reads
__global__ __launch_bounds__(512, 2) void gemm_kernel(const __bf16* __restrict__ X,
                                                      const __bf16* __restrict__ W,
                                                      float* __restrict__ out) {
    __shared__ __align__(16) unsigned char lds[131072];

    // T1: bijective XCD swizzle; 256 blocks = 8 XCDs x 32 (one expert per XCD)
    const int bid  = blockIdx.x;
    const int wgid = (bid & 7) * 32 + (bid >> 3);
    const int e    = wgid >> 5;
    const int tile = wgid & 31;
    const int brow = tile >> 2;   // 0..7
    const int bcol = tile & 3;    // 0..3

    const int t     = threadIdx.x;
    const int lane  = t & 63;
    const int wave  = t >> 6;
    const int wm    = wave >> 2;  // 0..1
    const int wn    = wave & 3;   // 0..3
    const int flane = lane & 15;

    const __bf16* Xt = X + (size_t)(e * TPE + brow * 256) * DIN_;
    const __bf16* Wt = W + (size_t)(e * DOUT_ + bcol * 256) * DIN_;

    // stage one kh-half (16 KiB): 2 GLD16/thread, linear dest, coalesced 64B/row source
    auto stage = [&](int j, bool isA, int kh) {
        if (j >= NT) return;
        const int buf = j & 1;
        const unsigned base = (isA ? 0u : 65536u) + (unsigned)(buf * 2 + kh) * 16384u;
        const __bf16* src = isA ? Xt : Wt;
        const int col = j * 64 + kh * 32 + (t & 3) * 8;
        #pragma unroll
        for (int i = 0; i < 2; ++i) {
            const unsigned p = (unsigned)i * 8192u + (unsigned)t * 16u;
            GLD(src + (size_t)(p >> 6) * DIN_ + col, &lds[base + p]);
        }
    };

    auto ldf = [&](unsigned base, int row) -> bf16x8 {
        return *(const bf16x8*)&lds[base + (unsigned)row * 64u + (unsigned)(lane >> 4) * 16u];
    };

    bf16x8 aA[4], aB[4], b0[4], b1[4];
    f32x4 acc[8][4] = {};

    #define ABASE(buf, kh) ((unsigned)((buf) * 2 + (kh)) * 16384u)
    #define BBASE(buf, kh) (65536u + (unsigned)((buf) * 2 + (kh)) * 16384u)
    #define PRE_A(dst, buf, kh, m0) \
        { _Pragma("unroll") for (int m_ = 0; m_ < 4; ++m_) \
            dst[m_] = ldf(ABASE(buf, kh), wm * 128 + ((m0) + m_) * 16 + flane); }
    #define PRE_B(dst, buf, kh) \
        { _Pragma("unroll") for (int n_ = 0; n_ < 4; ++n_) \
            dst[n_] = ldf(BBASE(buf, kh), wn * 64 + n_ * 16 + flane); }
    #define MFMA4x4(alo, aset, bset) \
        { _Pragma("unroll") for (int m_ = 0; m_ < 4; ++m_) \
            _Pragma("unroll") for (int n_ = 0; n_ < 4; ++n_) \
                acc[(alo) + m_][n_] = __builtin_amdgcn_mfma_f32_16x16x32_bf16( \
                    aset[m_], bset[n_], acc[(alo) + m_][n_], 0, 0, 0); }

    // prologue: tile0 all parts + tile1 {B-kh0,B-kh1,A-kh0}; order matters for gates
    stage(0, false, 0); stage(0, false, 1); stage(0, true, 0);
    stage(0, true, 1);  stage(1, false, 0); stage(1, false, 1); stage(1, true, 0);
    asm volatile("s_waitcnt vmcnt(8)" ::: "memory");   // tile0 kh0 parts landed
    __builtin_amdgcn_s_barrier();
    PRE_A(aA, 0, 0, 0);   // A-kh0(0) m0-3
    PRE_B(b0, 0, 0);      // B-kh0(0)

    for (int kt = 0; kt < NT; ++kt) {
        const int buf = kt & 1;

        // ---- phase 1: kh0 m0-3 (aA, b0) ----
        PRE_A(aB, buf, 0, 4);                 // for ph2
        stage(kt + 1, true, 1);               // A-kh1(kt+1) -> buf^1
        asm volatile("s_waitcnt lgkmcnt(4)" ::: "memory");
        __builtin_amdgcn_sched_barrier(0);
        __builtin_amdgcn_s_setprio(1);
        MFMA4x4(0, aA, b0);
        __builtin_amdgcn_s_setprio(0);
        if (kt < NT - 1) asm volatile("s_waitcnt vmcnt(8)" ::: "memory");
        else             asm volatile("s_waitcnt vmcnt(0)" ::: "memory");
        __builtin_amdgcn_s_barrier();

        // ---- phase 2: kh0 m4-7 (aB, b0) ----
        PRE_A(aA, buf, 1, 0);                 // for ph3
        PRE_B(b1, buf, 1);
        stage(kt + 2, false, 0);              // B-kh0(kt+2) -> buf
        asm volatile("s_waitcnt lgkmcnt(8)" ::: "memory");
        __builtin_amdgcn_sched_barrier(0);
        __builtin_amdgcn_s_setprio(1);
        MFMA4x4(4, aB, b0);
        __builtin_amdgcn_s_setprio(0);
        __builtin_amdgcn_s_barrier();

        // ---- phase 3: kh1 m0-3 (aA, b1) ----
        PRE_A(aB, buf, 1, 4);                 // for ph4
        asm volatile("s_waitcnt lgkmcnt(4)" ::: "memory");
        __builtin_amdgcn_sched_barrier(0);
        __builtin_amdgcn_s_setprio(1);
        MFMA4x4(0, aA, b1);
        __builtin_amdgcn_s_setprio(0);
        if (kt < NT - 2)      asm volatile("s_waitcnt vmcnt(4)" ::: "memory");
        else if (kt == NT - 2) asm volatile("s_waitcnt vmcnt(2)" ::: "memory");
        __builtin_amdgcn_s_barrier();

        // ---- phase 4: kh1 m4-7 (aB, b1) ----
        if (kt < NT - 1) {
            PRE_A(aA, buf ^ 1, 0, 0);         // next tile kh0 m0-3
            PRE_B(b0, buf ^ 1, 0);
        }
        stage(kt + 2, false, 1);              // B-kh1(kt+2) -> buf
        stage(kt + 2, true, 0);               // A-kh0(kt+2) -> buf
        if (kt < NT - 1) asm volatile("s_waitcnt lgkmcnt(8)" ::: "memory");
        else             asm volatile("s_waitcnt lgkmcnt(0)" ::: "memory");
        __builtin_amdgcn_sched_barrier(0);
        __builtin_amdgcn_s_setprio(1);
        MFMA4x4(4, aB, b1);
        __builtin_amdgcn_s_setprio(0);
        __builtin_amdgcn_s_barrier();
    }

    // epilogue: C/D mapping col = lane&15, row = (lane>>4)*4 + j
    const int orow0 = e * TPE + brow * 256 + wm * 128;
    const int ocol0 = bcol * 256 + wn * 64;
    const int rl = (lane >> 4) * 4;
    const int cl = lane & 15;
    #pragma unroll
    for (int m = 0; m < 8; ++m)
        #pragma unroll
        for (int n = 0; n < 4; ++n)
            #pragma unroll
            for (int j = 0; j < 4; ++j) {
                const int r = orow0 + m * 16 + rl + j;
                const int c = ocol0 + n * 16 + cl;
                out[(size_t)r * DOUT_ + c] = acc[m][n][j];
            }
}

extern "C" void kernel_launch(void* const* d_in, const int* in_sizes, int n_in,
                              void* d_out, int out_size, void* d_ws, size_t ws_size,
                              hipStream_t stream) {
    const float* x = (const float*)d_in[0];
    // d_in[1] = tokens_per_expert: reference assumes equal split, unused.
    const float* w = (const float*)d_in[2];
    float* out = (float*)d_out;

    __bf16* xq = (__bf16*)d_ws;
    __bf16* wq = (__bf16*)((char*)d_ws + (size_t)SEQ * DIN_ * sizeof(__bf16));

    quant_x_kernel<<<SEQ / 2, 256, 0, stream>>>(x, xq);
    quant_w_kernel<<<(NE_ * DOUT_ / 128) * (DIN_ / 128), 256, 0, stream>>>(w, wq);
    gemm_kernel<<<NE_ * (TPE / 256) * (DOUT_ / 256), 512, 0, stream>>>(xq, wq, out);
}

// Round 7
// 121.464 us; speedup vs baseline: 1.0041x; 1.0041x over previous
//
#include <hip/hip_runtime.h>
#include <hip/hip_bf16.h>
#include <hip/hip_fp8.h>

// Problem shape (fixed by setup_inputs)
#define SEQ   16384
#define DIN_  2048
#define DOUT_ 1024
#define NE_   8
#define TPE   (SEQ / NE_)   // 2048 tokens per expert
#define NT    (DIN_ / 64)   // 32 K-tiles of 64

typedef __bf16 bf16x8 __attribute__((ext_vector_type(8)));
typedef __bf16 bf16x4 __attribute__((ext_vector_type(4)));
typedef float  f32x4  __attribute__((ext_vector_type(4)));

// async global->LDS, 16B per lane. LDS dest must be wave-linear (base + lane*16).
#define GLD(gp, lp) __builtin_amdgcn_global_load_lds( \
    (const __attribute__((address_space(1))) unsigned int*)(gp), \
    (__attribute__((address_space(3))) unsigned int*)(lp), 16, 0, 0)

// Reference fp8_round with the tile-wide divide hoisted: r = v*(1/scale)
__device__ __forceinline__ float fp8_round_dq_m(float v, float sinv, float s) {
    float r = v * sinv;
    r = fminf(fmaxf(r, -448.0f), 448.0f);
    __hip_fp8_e4m3 q(r);   // OCP e4m3fn, RNE, saturated
    return (float)q * s;
}

// ---------------- activation quant-dequant: 1x128 tiles, 2 rows per block ----------------
__global__ __launch_bounds__(256) void quant_x_kernel(const float* __restrict__ X,
                                                      __bf16* __restrict__ Xq) {
    const int t    = threadIdx.x;
    const int lane = t & 63;
    const int wave = t >> 6;
    const int tile = wave * 4 + (lane >> 4);   // 0..15
    const int sub  = lane & 15;
    const size_t off = (size_t)tile * 128 + sub * 8;

    const int row0 = blockIdx.x * 2;
    const float* pa = X + (size_t)row0 * DIN_ + off;
    const float* pb = X + (size_t)(row0 + 1) * DIN_ + off;

    float4 a0 = *(const float4*)pa;
    float4 a1 = *(const float4*)(pa + 4);
    float4 b0 = *(const float4*)pb;
    float4 b1 = *(const float4*)(pb + 4);

    float ma = fmaxf(fmaxf(fmaxf(fabsf(a0.x), fabsf(a0.y)), fmaxf(fabsf(a0.z), fabsf(a0.w))),
                     fmaxf(fmaxf(fabsf(a1.x), fabsf(a1.y)), fmaxf(fabsf(a1.z), fabsf(a1.w))));
    float mb = fmaxf(fmaxf(fmaxf(fabsf(b0.x), fabsf(b0.y)), fmaxf(fabsf(b0.z), fabsf(b0.w))),
                     fmaxf(fmaxf(fabsf(b1.x), fabsf(b1.y)), fmaxf(fabsf(b1.z), fabsf(b1.w))));
    #pragma unroll
    for (int off2 = 1; off2 < 16; off2 <<= 1) {
        ma = fmaxf(ma, __shfl_xor(ma, off2, 64));
        mb = fmaxf(mb, __shfl_xor(mb, off2, 64));
    }

    const float sa = fmaxf(ma, 1e-12f) / 448.0f, sia = 1.0f / sa;
    const float sb = fmaxf(mb, 1e-12f) / 448.0f, sib = 1.0f / sb;

    bf16x8 oa, ob;
    oa[0] = (__bf16)fp8_round_dq_m(a0.x, sia, sa);
    oa[1] = (__bf16)fp8_round_dq_m(a0.y, sia, sa);
    oa[2] = (__bf16)fp8_round_dq_m(a0.z, sia, sa);
    oa[3] = (__bf16)fp8_round_dq_m(a0.w, sia, sa);
    oa[4] = (__bf16)fp8_round_dq_m(a1.x, sia, sa);
    oa[5] = (__bf16)fp8_round_dq_m(a1.y, sia, sa);
    oa[6] = (__bf16)fp8_round_dq_m(a1.z, sia, sa);
    oa[7] = (__bf16)fp8_round_dq_m(a1.w, sia, sa);
    ob[0] = (__bf16)fp8_round_dq_m(b0.x, sib, sb);
    ob[1] = (__bf16)fp8_round_dq_m(b0.y, sib, sb);
    ob[2] = (__bf16)fp8_round_dq_m(b0.z, sib, sb);
    ob[3] = (__bf16)fp8_round_dq_m(b0.w, sib, sb);
    ob[4] = (__bf16)fp8_round_dq_m(b1.x, sib, sb);
    ob[5] = (__bf16)fp8_round_dq_m(b1.y, sib, sb);
    ob[6] = (__bf16)fp8_round_dq_m(b1.z, sib, sb);
    ob[7] = (__bf16)fp8_round_dq_m(b1.w, sib, sb);
    *(bf16x8*)(Xq + (size_t)row0 * DIN_ + off) = oa;
    *(bf16x8*)(Xq + (size_t)(row0 + 1) * DIN_ + off) = ob;
}

// ---------------- weight quant-dequant: 128x128 blocks ----------------
__global__ __launch_bounds__(256) void quant_w_kernel(const float* __restrict__ W,
                                                      __bf16* __restrict__ Wq) {
    const int rb = blockIdx.x >> 4;
    const int cb = blockIdx.x & 15;
    const int t  = threadIdx.x;

    const float* base = W + (size_t)(rb * 128) * DIN_ + cb * 128;
    const int r0 = t >> 5;
    const int c0 = (t & 31) * 4;

    float4 v[16];
    float m = 0.0f;
    #pragma unroll
    for (int i = 0; i < 16; ++i) {
        v[i] = *(const float4*)(base + (size_t)(i * 8 + r0) * DIN_ + c0);
        m = fmaxf(m, fmaxf(fmaxf(fabsf(v[i].x), fabsf(v[i].y)),
                           fmaxf(fabsf(v[i].z), fabsf(v[i].w))));
    }
    #pragma unroll
    for (int off = 1; off < 64; off <<= 1)
        m = fmaxf(m, __shfl_xor(m, off, 64));
    __shared__ float smx[4];
    if ((t & 63) == 0) smx[t >> 6] = m;
    __syncthreads();
    const float amax = fmaxf(fmaxf(smx[0], smx[1]), fmaxf(smx[2], smx[3]));
    const float s    = fmaxf(amax, 1e-12f) / 448.0f;
    const float sinv = 1.0f / s;

    __bf16* obase = Wq + (size_t)(rb * 128) * DIN_ + cb * 128;
    #pragma unroll
    for (int i = 0; i < 16; ++i) {
        bf16x4 o;
        o[0] = (__bf16)fp8_round_dq_m(v[i].x, sinv, s);
        o[1] = (__bf16)fp8_round_dq_m(v[i].y, sinv, s);
        o[2] = (__bf16)fp8_round_dq_m(v[i].z, sinv, s);
        o[3] = (__bf16)fp8_round_dq_m(v[i].w, sinv, s);
        *(bf16x4*)(obase + (size_t)(i * 8 + r0) * DIN_ + c0) = o;
    }
}

// ---------------- grouped GEMM: 256x256, BK=64, pre-read pipelined + swizzled LDS ----
// LDS 128 KiB = 8 kh-half regions [256 rows][64 B]:
//   A(buf,kh) @ (buf*2+kh)*16384 ; B(buf,kh) @ 65536 + (buf*2+kh)*16384.
// SWIZZLE (restored from R2; R6 dropped it -> 8-way bank conflict):
//   byte p ^= ((p>>7)&3)<<4  (slot ^= (row>>1)&3). Rows 0..15 at a fixed slot then
//   spread over 8 banks x 2 lanes = conflict-free. Applied both-sides: linear GLD
//   dest + inverse-swizzled global source + swizzled ds_read.
// Pre-read schedule (reads issued ONE phase ahead, drain under MFMA):
//   ph4(kt-1): aA=A-kh0 m0-3 + b0=B-kh0   [8]   -> used ph1
//   ph1:       aB=A-kh0 m4-7              [4]   -> used ph2
//   ph2:       aA=A-kh1 m0-3 + b1=B-kh1   [8]   -> used ph3
//   ph3:       aB=A-kh1 m4-7              [4]   -> used ph4
// Counted waits: ph1 lgkm(4), ph2 lgkm(8), ph3 lgkm(4), ph4 lgkm(8|0).
// Stage slots: ph1: A-kh1(kt+1) | ph2: B-kh0(kt+2) | ph4: B-kh1(kt+2), A-kh0(kt+2).
// vmcnt gates before the inter-phase barrier:
//   end-ph1: vmcnt(8) [kt==NT-1: 0] ; end-ph3: vmcnt(4) [kt==NT-2: 2; NT-1: none].
__global__ __launch_bounds__(512, 2) void gemm_kernel(const __bf16* __restrict__ X,
                                                      const __bf16* __restrict__ W,
                                                      float* __restrict__ out) {
    __shared__ __align__(16) unsigned char lds[131072];

    // T1: bijective XCD swizzle; 256 blocks = 8 XCDs x 32 (one expert per XCD)
    const int bid  = blockIdx.x;
    const int wgid = (bid & 7) * 32 + (bid >> 3);
    const int e    = wgid >> 5;
    const int tile = wgid & 31;
    const int brow = tile >> 2;   // 0..7
    const int bcol = tile & 3;    // 0..3

    const int t     = threadIdx.x;
    const int lane  = t & 63;
    const int wave  = t >> 6;
    const int wm    = wave >> 2;  // 0..1
    const int wn    = wave & 3;   // 0..3
    const int flane = lane & 15;

    const __bf16* Xt = X + (size_t)(e * TPE + brow * 256) * DIN_;
    const __bf16* Wt = W + (size_t)(e * DOUT_ + bcol * 256) * DIN_;

    // stage one kh-half (16 KiB): 2 GLD16/thread, linear dest, inverse-swizzled source
    auto stage = [&](int j, bool isA, int kh) {
        if (j >= NT) return;
        const int buf = j & 1;
        const unsigned base = (isA ? 0u : 65536u) + (unsigned)(buf * 2 + kh) * 16384u;
        const __bf16* src = isA ? Xt : Wt;
        #pragma unroll
        for (int i = 0; i < 2; ++i) {
            const unsigned p = (unsigned)i * 8192u + (unsigned)t * 16u;
            const unsigned q = p ^ (((p >> 7) & 3u) << 4);   // involution
            GLD(src + (size_t)(q >> 6) * DIN_ + j * 64 + kh * 32 + ((q & 63u) >> 1),
                &lds[base + p]);
        }
    };

    auto ldf = [&](unsigned base, int row) -> bf16x8 {
        unsigned p = (unsigned)row * 64u + (unsigned)(lane >> 4) * 16u;
        p ^= ((p >> 7) & 3u) << 4;
        return *(const bf16x8*)&lds[base + p];
    };

    bf16x8 aA[4], aB[4], b0[4], b1[4];
    f32x4 acc[8][4] = {};

    #define ABASE(buf, kh) ((unsigned)((buf) * 2 + (kh)) * 16384u)
    #define BBASE(buf, kh) (65536u + (unsigned)((buf) * 2 + (kh)) * 16384u)
    #define PRE_A(dst, buf, kh, m0) \
        { _Pragma("unroll") for (int m_ = 0; m_ < 4; ++m_) \
            dst[m_] = ldf(ABASE(buf, kh), wm * 128 + ((m0) + m_) * 16 + flane); }
    #define PRE_B(dst, buf, kh) \
        { _Pragma("unroll") for (int n_ = 0; n_ < 4; ++n_) \
            dst[n_] = ldf(BBASE(buf, kh), wn * 64 + n_ * 16 + flane); }
    #define MFMA4x4(alo, aset, bset) \
        { _Pragma("unroll") for (int m_ = 0; m_ < 4; ++m_) \
            _Pragma("unroll") for (int n_ = 0; n_ < 4; ++n_) \
                acc[(alo) + m_][n_] = __builtin_amdgcn_mfma_f32_16x16x32_bf16( \
                    aset[m_], bset[n_], acc[(alo) + m_][n_], 0, 0, 0); }

    // prologue: tile0 all parts + tile1 {B-kh0,B-kh1,A-kh0}; order matters for gates
    stage(0, false, 0); stage(0, false, 1); stage(0, true, 0);
    stage(0, true, 1);  stage(1, false, 0); stage(1, false, 1); stage(1, true, 0);
    asm volatile("s_waitcnt vmcnt(8)" ::: "memory");   // tile0 kh0 parts landed
    __builtin_amdgcn_s_barrier();
    PRE_A(aA, 0, 0, 0);   // A-kh0(0) m0-3
    PRE_B(b0, 0, 0);      // B-kh0(0)

    for (int kt = 0; kt < NT; ++kt) {
        const int buf = kt & 1;

        // ---- phase 1: kh0 m0-3 (aA, b0) ----
        PRE_A(aB, buf, 0, 4);                 // for ph2
        stage(kt + 1, true, 1);               // A-kh1(kt+1) -> buf^1
        asm volatile("s_waitcnt lgkmcnt(4)" ::: "memory");
        __builtin_amdgcn_sched_barrier(0);
        __builtin_amdgcn_s_setprio(1);
        MFMA4x4(0, aA, b0);
        __builtin_amdgcn_s_setprio(0);
        if (kt < NT - 1) asm volatile("s_waitcnt vmcnt(8)" ::: "memory");
        else             asm volatile("s_waitcnt vmcnt(0)" ::: "memory");
        __builtin_amdgcn_s_barrier();

        // ---- phase 2: kh0 m4-7 (aB, b0) ----
        PRE_A(aA, buf, 1, 0);                 // for ph3
        PRE_B(b1, buf, 1);
        stage(kt + 2, false, 0);              // B-kh0(kt+2) -> buf
        asm volatile("s_waitcnt lgkmcnt(8)" ::: "memory");
        __builtin_amdgcn_sched_barrier(0);
        __builtin_amdgcn_s_setprio(1);
        MFMA4x4(4, aB, b0);
        __builtin_amdgcn_s_setprio(0);
        __builtin_amdgcn_s_barrier();

        // ---- phase 3: kh1 m0-3 (aA, b1) ----
        PRE_A(aB, buf, 1, 4);                 // for ph4
        asm volatile("s_waitcnt lgkmcnt(4)" ::: "memory");
        __builtin_amdgcn_sched_barrier(0);
        __builtin_amdgcn_s_setprio(1);
        MFMA4x4(0, aA, b1);
        __builtin_amdgcn_s_setprio(0);
        if (kt < NT - 2)      asm volatile("s_waitcnt vmcnt(4)" ::: "memory");
        else if (kt == NT - 2) asm volatile("s_waitcnt vmcnt(2)" ::: "memory");
        __builtin_amdgcn_s_barrier();

        // ---- phase 4: kh1 m4-7 (aB, b1) ----
        if (kt < NT - 1) {
            PRE_A(aA, buf ^ 1, 0, 0);         // next tile kh0 m0-3
            PRE_B(b0, buf ^ 1, 0);
        }
        stage(kt + 2, false, 1);              // B-kh1(kt+2) -> buf
        stage(kt + 2, true, 0);               // A-kh0(kt+2) -> buf
        if (kt < NT - 1) asm volatile("s_waitcnt lgkmcnt(8)" ::: "memory");
        else             asm volatile("s_waitcnt lgkmcnt(0)" ::: "memory");
        __builtin_amdgcn_sched_barrier(0);
        __builtin_amdgcn_s_setprio(1);
        MFMA4x4(4, aB, b1);
        __builtin_amdgcn_s_setprio(0);
        __builtin_amdgcn_s_barrier();
    }

    // epilogue: C/D mapping col = lane&15, row = (lane>>4)*4 + j
    const int orow0 = e * TPE + brow * 256 + wm * 128;
    const int ocol0 = bcol * 256 + wn * 64;
    const int rl = (lane >> 4) * 4;
    const int cl = lane & 15;
    #pragma unroll
    for (int m = 0; m < 8; ++m)
        #pragma unroll
        for (int n = 0; n < 4; ++n)
            #pragma unroll
            for (int j = 0; j < 4; ++j) {
                const int r = orow0 + m * 16 + rl + j;
                const int c = ocol0 + n * 16 + cl;
                out[(size_t)r * DOUT_ + c] = acc[m][n][j];
            }
}

extern "C" void kernel_launch(void* const* d_in, const int* in_sizes, int n_in,
                              void* d_out, int out_size, void* d_ws, size_t ws_size,
                              hipStream_t stream) {
    const float* x = (const float*)d_in[0];
    // d_in[1] = tokens_per_expert: reference assumes equal split, unused.
    const float* w = (const float*)d_in[2];
    float* out = (float*)d_out;

    __bf16* xq = (__bf16*)d_ws;
    __bf16* wq = (__bf16*)((char*)d_ws + (size_t)SEQ * DIN_ * sizeof(__bf16));

    quant_x_kernel<<<SEQ / 2, 256, 0, stream>>>(x, xq);
    quant_w_kernel<<<(NE_ * DOUT_ / 128) * (DIN_ / 128), 256, 0, stream>>>(w, wq);
    gemm_kernel<<<NE_ * (TPE / 256) * (DOUT_ / 256), 512, 0, stream>>>(xq, wq, out);
}